// Round 4
// baseline (741.208 us; speedup 1.0000x reference)
//
#include <hip/hip_runtime.h>

// CrossAttention decode, algebraically collapsed (all fp32):
//   q[b,h,:]   = ((x1@We1+be1)@Wq+bq) head-sliced
//   u[b,h,c]   = sum_d WkT[h*64+d,c]*q[b,h,d]
//   w[b,h,i]   = sum_c u[b,h,c]*We2t[c,i]          (K-proj folded)
//   score[b,h,s] = x2[b,s,:].w[b,h,:]              (134MB stream #1)
//     (K-side biases constant over s -> cancel in softmax; dropped)
//   a = softmax(score/8)
//   g[b,h,i]   = sum_s a[b,h,s]*x3[b,s,i]          (134MB stream #2, atomics)
//   G2[b,h,c]  = g@We2 + be2;  av = G2@Wv_h + bv;  out = av@Wo + bo
// 11 serial dispatches. Measured floor includes ~300us of harness reset
// (537MB d_ws poison fill at 86% HBM + d_in restore) we cannot control.

#define DIN 512
#define DD  1024
#define NH  16
#define HD  64
#define BB  16
#define SS  4096

__device__ __forceinline__ int wave_id() {
    return __builtin_amdgcn_readfirstlane((int)(threadIdx.x >> 6));
}

__device__ __forceinline__ void tile_transpose(const float* __restrict__ in,
                                               float* __restrict__ out,
                                               int R, int C, int rblk, int cblk) {
    __shared__ float tl[32][33];
    const int tx = threadIdx.x & 31, ty = threadIdx.x >> 5;  // ty 0..7
    const int c0 = cblk * 32, r0 = rblk * 32;
#pragma unroll
    for (int k = 0; k < 4; ++k)
        tl[ty + k * 8][tx] = in[(size_t)(r0 + ty + k * 8) * C + c0 + tx];
    __syncthreads();
#pragma unroll
    for (int k = 0; k < 4; ++k)
        out[(size_t)(c0 + ty + k * 8) * R + r0 + tx] = tl[tx][ty + k * 8];
}

// One fused prep dispatch:
//  blocks [0,512):     We2 [512][1024] -> We2t [1024][512]
//  blocks [512,1536):  Wk  [1024][1024] -> WkT [1024][1024]
//  blocks [1536,1552): bias-init x1e/qb/av/out, zero-init g
__global__ __launch_bounds__(256) void k_prep(const float* __restrict__ We2,
                                              const float* __restrict__ Wk,
                                              const float* __restrict__ be1,
                                              const float* __restrict__ bq,
                                              const float* __restrict__ bv,
                                              const float* __restrict__ bo,
                                              float* __restrict__ We2t,
                                              float* __restrict__ WkT,
                                              float* __restrict__ x1e,
                                              float* __restrict__ qb,
                                              float* __restrict__ av,
                                              float* __restrict__ out,
                                              float* __restrict__ g) {
    const int bx = blockIdx.x;
    if (bx < 512) {
        tile_transpose(We2, We2t, DIN, DD, bx >> 5, bx & 31);
    } else if (bx < 1536) {
        const int lb = bx - 512;
        tile_transpose(Wk, WkT, DD, DD, lb >> 5, lb & 31);
    } else {
        const int b = bx - 1536;
#pragma unroll
        for (int k = 0; k < 4; ++k) {
            const int c = k * 256 + threadIdx.x;
            x1e[(size_t)b * DD + c] = be1[c];
            qb[(size_t)b * DD + c]  = bq[c];
            av[(size_t)b * DD + c]  = bv[c];
            out[(size_t)b * DD + c] = bo[c];
        }
#pragma unroll
        for (int k = 0; k < 32; ++k)
            g[(size_t)b * 8192 + k * 256 + threadIdx.x] = 0.f;
    }
}

// out[r][c] (+)= sum_i in[r][i]*W[i][c] for 16 rows r = by*16..+16.
// grid (N/64, R/16, KS). KS==1: plain store (+bias). KS>1: atomicAdd into
// bias-initialized out. 16 row accumulators amortize each coalesced W load.
template <int K, int N, int KS, bool HASB>
__global__ __launch_bounds__(256) void k_bmv2(const float* __restrict__ in,
                                              const float* __restrict__ W,
                                              const float* __restrict__ bias,
                                              float* __restrict__ out) {
    const int l = threadIdx.x & 63;
    const int c = blockIdx.x * 64 + l;
    const int wv = wave_id();
    constexpr int KCH = K / KS;
    constexpr int SUB = KCH / 4;
    const float* inb = in + (size_t)blockIdx.y * 16 * K;  // uniform -> s_load
    float acc[16];
#pragma unroll
    for (int r = 0; r < 16; ++r) acc[r] = 0.f;
    const int i0 = blockIdx.z * KCH + wv * SUB;
#pragma unroll 4
    for (int i = i0; i < i0 + SUB; ++i) {
        const float wval = W[(size_t)i * N + c];  // coalesced 256B/wave
#pragma unroll
        for (int r = 0; r < 16; ++r) acc[r] += inb[(size_t)r * K + i] * wval;
    }
    __shared__ float red[4][16][64];
#pragma unroll
    for (int r = 0; r < 16; ++r) red[wv][r][l] = acc[r];
    __syncthreads();
#pragma unroll
    for (int k = 0; k < 4; ++k) {
        const int r = wv + k * 4;
        float v = red[0][r][l] + red[1][r][l] + red[2][r][l] + red[3][r][l];
        float* dst = out + ((size_t)blockIdx.y * 16 + r) * N + c;
        if (KS == 1) {
            if (HASB) v += bias[c];
            *dst = v;
        } else {
            atomicAdd(dst, v);
        }
    }
}

// u[b*16+h][c] = sum_d q[b][h*64+d]*WkT[h*64+d][c].  grid (1024/64, 16 h).
__global__ __launch_bounds__(256) void k_u2(const float* __restrict__ q,
                                            const float* __restrict__ WkT,
                                            float* __restrict__ u) {
    const int h = blockIdx.y;
    const int l = threadIdx.x & 63;
    const int c = blockIdx.x * 64 + l;
    const int wv = wave_id();
    float acc[16];
#pragma unroll
    for (int bb = 0; bb < 16; ++bb) acc[bb] = 0.f;
#pragma unroll 4
    for (int dk = 0; dk < 16; ++dk) {
        const int d = wv * 16 + dk;
        const float wval = WkT[(size_t)(h * HD + d) * DD + c];  // coalesced
#pragma unroll
        for (int bb = 0; bb < 16; ++bb)
            acc[bb] += q[(size_t)bb * DD + h * HD + d] * wval;  // s_load
    }
    __shared__ float red[4][16][64];
#pragma unroll
    for (int bb = 0; bb < 16; ++bb) red[wv][bb][l] = acc[bb];
    __syncthreads();
#pragma unroll
    for (int k = 0; k < 4; ++k) {
        const int bb = wv + k * 4;
        float v = red[0][bb][l] + red[1][bb][l] + red[2][bb][l] + red[3][bb][l];
        u[((size_t)bb * NH + h) * DD + c] = v;
    }
}

// score[b][h][s] = x2[b][s][:].w[b][h][:].  grid (4096/64, 16 b), block 256.
// Double-buffered: 8 stages of 64 cols; register-prefetch stage kt+1 while
// computing stage kt from XOR-swizzled LDS; one barrier per stage.
__global__ __launch_bounds__(256) void k_scores(const float* __restrict__ x2,
                                                const float* __restrict__ w,
                                                float* __restrict__ sc) {
    __shared__ float4 tile[2][64 * 16];  // 2 x 16KB
    const int b = blockIdx.y;
    const int s0 = blockIdx.x * 64;
    const int l = threadIdx.x & 63;
    const int h0 = wave_id() * 4;
    const float4* x2f = (const float4*)x2 + ((size_t)b * SS + s0) * (DIN / 4);
    const float4* wp = (const float4*)(w + ((size_t)b * NH + h0) * DIN);

    // stage-load helper indices: idx = tid + k*256; row = idx>>4, c4 = idx&15
    float4 pf[4];
#pragma unroll
    for (int k = 0; k < 4; ++k) {
        const int idx = threadIdx.x + k * 256;
        pf[k] = x2f[(idx >> 4) * (DIN / 4) + (idx & 15)];
    }
    float a0 = 0.f, a1 = 0.f, a2 = 0.f, a3 = 0.f;
#pragma unroll
    for (int kt = 0; kt < 8; ++kt) {
        float4* buf = tile[kt & 1];
#pragma unroll
        for (int k = 0; k < 4; ++k) {
            const int idx = threadIdx.x + k * 256;
            const int row = idx >> 4, c4 = idx & 15;
            buf[row * 16 + (c4 ^ (row & 7))] = pf[k];
        }
        __syncthreads();
        if (kt < 7) {
#pragma unroll
            for (int k = 0; k < 4; ++k) {
                const int idx = threadIdx.x + k * 256;
                pf[k] = x2f[(idx >> 4) * (DIN / 4) + (kt + 1) * 16 + (idx & 15)];
            }
        }
#pragma unroll
        for (int c4 = 0; c4 < 16; ++c4) {
            const float4 x = buf[l * 16 + (c4 ^ (l & 7))];
            const float4 q0 = wp[kt * 16 + c4];            // uniform -> s_load
            const float4 q1 = wp[128 + kt * 16 + c4];
            const float4 q2 = wp[256 + kt * 16 + c4];
            const float4 q3 = wp[384 + kt * 16 + c4];
            a0 += x.x * q0.x + x.y * q0.y + x.z * q0.z + x.w * q0.w;
            a1 += x.x * q1.x + x.y * q1.y + x.z * q1.z + x.w * q1.w;
            a2 += x.x * q2.x + x.y * q2.y + x.z * q2.z + x.w * q2.w;
            a3 += x.x * q3.x + x.y * q3.y + x.z * q3.z + x.w * q3.w;
        }
    }
    const size_t base = ((size_t)b * NH + h0) * SS + s0 + l;
    sc[base + 0 * SS] = a0;
    sc[base + 1 * SS] = a1;
    sc[base + 2 * SS] = a2;
    sc[base + 3 * SS] = a3;
}

// In-place softmax over rows of 4096 (logit scale 1/8), float4 I/O. grid 256.
__global__ __launch_bounds__(256) void k_softmax(float* __restrict__ sc) {
    float4* row = (float4*)(sc + (size_t)blockIdx.x * SS);
    float4 v[4];
    float m = -1e30f;
#pragma unroll
    for (int j = 0; j < 4; ++j) {
        v[j] = row[threadIdx.x + j * 256];
        m = fmaxf(m, fmaxf(fmaxf(v[j].x, v[j].y), fmaxf(v[j].z, v[j].w)));
    }
    __shared__ float red[256];
    red[threadIdx.x] = m;
    __syncthreads();
    for (int s = 128; s > 0; s >>= 1) {
        if (threadIdx.x < (unsigned)s)
            red[threadIdx.x] = fmaxf(red[threadIdx.x], red[threadIdx.x + s]);
        __syncthreads();
    }
    m = red[0];
    __syncthreads();
    float sum = 0.f;
#pragma unroll
    for (int j = 0; j < 4; ++j) {
        v[j].x = expf((v[j].x - m) * 0.125f);
        v[j].y = expf((v[j].y - m) * 0.125f);
        v[j].z = expf((v[j].z - m) * 0.125f);
        v[j].w = expf((v[j].w - m) * 0.125f);
        sum += v[j].x + v[j].y + v[j].z + v[j].w;
    }
    red[threadIdx.x] = sum;
    __syncthreads();
    for (int s = 128; s > 0; s >>= 1) {
        if (threadIdx.x < (unsigned)s) red[threadIdx.x] += red[threadIdx.x + s];
        __syncthreads();
    }
    const float inv = 1.f / red[0];
#pragma unroll
    for (int j = 0; j < 4; ++j) {
        v[j].x *= inv; v[j].y *= inv; v[j].z *= inv; v[j].w *= inv;
        row[threadIdx.x + j * 256] = v[j];
    }
}

// g[b][h][i] (+)= sum_s a[b][h][s]*x3[b][s][i] over this block's s-chunk.
// grid (nch=32, 16 b), block 256. Wave owns its own s-subrange for ALL 16
// heads; lane covers cols l*4..+4 and 256+l*4..+4 (contiguous 1KB wave
// loads). LDS cross-wave reduce, then atomicAdd into zero-initialized g.
__global__ __launch_bounds__(256) void k_gpart(const float* __restrict__ x3,
                                               const float* __restrict__ a,
                                               float* __restrict__ g,
                                               int schunk) {
    const int b = blockIdx.y, ch = blockIdx.x;
    const int wv = wave_id();
    const int l = threadIdx.x & 63;
    const int sub = schunk >> 2;
    const int sbeg = ch * schunk + wv * sub;
    const float* ar = a + (size_t)b * NH * SS;  // uniform
    float acc[16][8];
#pragma unroll
    for (int h = 0; h < 16; ++h)
#pragma unroll
        for (int j = 0; j < 8; ++j) acc[h][j] = 0.f;

#pragma unroll 2
    for (int s = sbeg; s < sbeg + sub; ++s) {
        const float4* xr = (const float4*)(x3 + ((size_t)b * SS + s) * DIN);
        const float4 xa = xr[l];
        const float4 xb = xr[l + 64];
        const float xv[8] = {xa.x, xa.y, xa.z, xa.w, xb.x, xb.y, xb.z, xb.w};
#pragma unroll
        for (int h = 0; h < 16; ++h) {
            const float wh = ar[h * SS + s];  // uniform -> s_load
#pragma unroll
            for (int j = 0; j < 8; ++j) acc[h][j] += wh * xv[j];
        }
    }

    __shared__ float red[4][2048];  // 32KB, reused for 4 head-groups
    for (int hg = 0; hg < 4; ++hg) {
        __syncthreads();
#pragma unroll
        for (int hh = 0; hh < 4; ++hh) {
            float* dst = &red[wv][hh * 512];
            const int hs = hg * 4 + hh;
            *(float4*)(dst + l * 4) =
                make_float4(acc[hs][0], acc[hs][1], acc[hs][2], acc[hs][3]);
            *(float4*)(dst + 256 + l * 4) =
                make_float4(acc[hs][4], acc[hs][5], acc[hs][6], acc[hs][7]);
        }
        __syncthreads();
        const int idx = threadIdx.x * 8;
        const int hh = idx >> 9;
        const int i = idx & 511;
        float* dst = g + ((size_t)b * NH + hg * 4 + hh) * DIN + i;
#pragma unroll
        for (int j = 0; j < 8; ++j) {
            const float o =
                red[0][idx + j] + red[1][idx + j] + red[2][idx + j] + red[3][idx + j];
            atomicAdd(dst + j, o);
        }
    }
}

// av[b][h*64+l] (+)= sum_c G2[b*16+h][c]*Wv[c][h*64+l] over a 128-c chunk.
// grid (16 h, 8 chunks) = 128 blocks; atomicAdd into bv-initialized av.
__global__ __launch_bounds__(256) void k_av_at(const float* __restrict__ G2,
                                               const float* __restrict__ Wv,
                                               float* __restrict__ av) {
    const int h = blockIdx.x;
    const int l = threadIdx.x & 63;
    const int wv = wave_id();
    const int c0 = blockIdx.y * 128 + wv * 32;
    float acc[16];
#pragma unroll
    for (int bb = 0; bb < 16; ++bb) acc[bb] = 0.f;
#pragma unroll 4
    for (int c = c0; c < c0 + 32; ++c) {
        const float wval = Wv[(size_t)c * DD + h * HD + l];  // coalesced
#pragma unroll
        for (int bb = 0; bb < 16; ++bb)
            acc[bb] += G2[((size_t)bb * NH + h) * DD + c] * wval;  // s_load
    }
    __shared__ float red[4][16][64];
#pragma unroll
    for (int bb = 0; bb < 16; ++bb) red[wv][bb][l] = acc[bb];
    __syncthreads();
#pragma unroll
    for (int k = 0; k < 4; ++k) {
        const int bb = wv + k * 4;
        float v = red[0][bb][l] + red[1][bb][l] + red[2][bb][l] + red[3][bb][l];
        atomicAdd(&av[(size_t)bb * DD + h * HD + l], v);
    }
}

extern "C" void kernel_launch(void* const* d_in, const int* in_sizes, int n_in,
                              void* d_out, int out_size, void* d_ws, size_t ws_size,
                              hipStream_t stream) {
    const float* x1  = (const float*)d_in[0];
    const float* x2  = (const float*)d_in[1];
    const float* x3  = (const float*)d_in[2];
    const float* We1 = (const float*)d_in[3];
    const float* be1 = (const float*)d_in[4];
    const float* We2 = (const float*)d_in[5];
    const float* be2 = (const float*)d_in[6];
    const float* Wq  = (const float*)d_in[7];
    const float* bq  = (const float*)d_in[8];
    const float* Wk  = (const float*)d_in[9];
    const float* bk  = (const float*)d_in[10];  // cancels in softmax (unused)
    const float* Wv  = (const float*)d_in[11];
    const float* bv  = (const float*)d_in[12];
    const float* Wo  = (const float*)d_in[13];
    const float* bo  = (const float*)d_in[14];
    (void)bk;
    float* out = (float*)d_out;

    char* ws = (char*)d_ws;
    size_t off = 0;
    auto alloc = [&](size_t bytes) -> void* {
        void* p = ws + off;
        off = (off + bytes + 255) & ~(size_t)255;
        return p;
    };
    float* We2t = (float*)alloc((size_t)DD * DIN * 4);  // [1024][512]
    float* WkT  = (float*)alloc((size_t)DD * DD * 4);   // [1024][1024]
    float* x1e  = (float*)alloc((size_t)BB * DD * 4);
    float* qb   = (float*)alloc((size_t)BB * DD * 4);
    float* u    = (float*)alloc((size_t)BB * NH * DD * 4);
    float* wv_  = (float*)alloc((size_t)BB * NH * DIN * 4);
    float* sc   = (float*)alloc((size_t)BB * NH * SS * 4);
    float* g    = (float*)alloc((size_t)BB * NH * DIN * 4);
    float* G2   = (float*)alloc((size_t)BB * NH * DD * 4);
    float* av   = (float*)alloc((size_t)BB * DD * 4);

    const int nch = 32;
    const int schunk = SS / nch;

    // prep: transposes + bias/zero inits (one dispatch)
    k_prep<<<1552, 256, 0, stream>>>(We2, Wk, be1, bq, bv, bo,
                                     We2t, WkT, x1e, qb, av, out, g);
    // x1e += x1@We1   (K=512, KS=8 -> 128 blocks)
    k_bmv2<DIN, DD, 8, false><<<dim3(DD / 64, 1, 8), 256, 0, stream>>>(x1, We1, nullptr, x1e);
    // qb += x1e@Wq    (K=1024, KS=8 -> 128 blocks)
    k_bmv2<DD, DD, 8, false><<<dim3(DD / 64, 1, 8), 256, 0, stream>>>(x1e, Wq, nullptr, qb);
    k_u2<<<dim3(DD / 64, NH), 256, 0, stream>>>(qb, WkT, u);
    // w = u@We2t      (R=256 -> 128 blocks)
    k_bmv2<DD, DIN, 1, false><<<dim3(DIN / 64, BB * NH / 16, 1), 256, 0, stream>>>(u, We2t, nullptr, wv_);
    k_scores<<<dim3(SS / 64, BB), 256, 0, stream>>>(x2, wv_, sc);
    k_softmax<<<BB * NH, 256, 0, stream>>>(sc);
    k_gpart<<<dim3(nch, BB), 256, 0, stream>>>(x3, sc, g, schunk);
    // G2 = g@We2+be2  (R=256 -> 256 blocks)
    k_bmv2<DIN, DD, 1, true><<<dim3(DD / 64, BB * NH / 16, 1), 256, 0, stream>>>(g, We2, be2, G2);
    k_av_at<<<dim3(NH, 8), 256, 0, stream>>>(G2, Wv, av);
    // out += av@Wo    (K=1024, KS=8 -> 128 blocks)
    k_bmv2<DD, DD, 8, false><<<dim3(DD / 64, 1, 8), 256, 0, stream>>>(av, Wo, nullptr, out);
}

// Round 5
// 465.769 us; speedup vs baseline: 1.5914x; 1.5914x over previous
//
#include <hip/hip_runtime.h>

// CrossAttention decode, algebraically collapsed (all fp32):
//   q[b,h,:]   = ((x1@We1+be1)@Wq+bq) head-sliced
//   u[b,h,c]   = sum_d WkT[h*64+d,c]*q[b,h,d]
//   w[b,h,i]   = sum_c u[b,h,c]*We2t[c,i]          (K-proj folded)
//   score[b,h,s] = x2[b,s,:].w[b,h,:]              (134MB stream #1)
//     (K-side biases constant over s -> cancel in softmax; dropped)
//   a = softmax(score/8)
//   g[b,h,i]   = sum_s a[b,h,s]*x3[b,s,i]          (134MB stream #2)
//   G2[b,h,c]  = g@We2 + be2;  av = G2@Wv_h + bv;  out = av@Wo + bo
// Lessons baked in: no per-element global atomics on hot paths (R4: 4.2M
// atomicAdds = 134MB HBM RMW traffic); LDS tiles padded to stride 33
// float4s (banks 4*(row+c4) mod 32 uniform -> conflict-free); keep VGPR
// low in k_scores (R4 prefetch hit the 256-VGPR cliff, occupancy 3.6%).

#define DIN 512
#define DD  1024
#define NH  16
#define HD  64
#define BB  16
#define SS  4096

__device__ __forceinline__ int wave_id() {
    return __builtin_amdgcn_readfirstlane((int)(threadIdx.x >> 6));
}

__device__ __forceinline__ void tile_transpose(const float* __restrict__ in,
                                               float* __restrict__ out,
                                               int R, int C, int rblk, int cblk) {
    __shared__ float tl[32][33];
    const int tx = threadIdx.x & 31, ty = threadIdx.x >> 5;  // ty 0..7
    const int c0 = cblk * 32, r0 = rblk * 32;
#pragma unroll
    for (int k = 0; k < 4; ++k)
        tl[ty + k * 8][tx] = in[(size_t)(r0 + ty + k * 8) * C + c0 + tx];
    __syncthreads();
#pragma unroll
    for (int k = 0; k < 4; ++k)
        out[(size_t)(c0 + ty + k * 8) * R + r0 + tx] = tl[tx][ty + k * 8];
}

// One fused prep dispatch:
//  blocks [0,512):     We2 [512][1024] -> We2t [1024][512]
//  blocks [512,1536):  Wk  [1024][1024] -> WkT [1024][1024]
//  blocks [1536,1552): bias-init x1e/qb/av/out (atomic targets)
__global__ __launch_bounds__(256) void k_prep(const float* __restrict__ We2,
                                              const float* __restrict__ Wk,
                                              const float* __restrict__ be1,
                                              const float* __restrict__ bq,
                                              const float* __restrict__ bv,
                                              const float* __restrict__ bo,
                                              float* __restrict__ We2t,
                                              float* __restrict__ WkT,
                                              float* __restrict__ x1e,
                                              float* __restrict__ qb,
                                              float* __restrict__ av,
                                              float* __restrict__ out) {
    const int bx = blockIdx.x;
    if (bx < 512) {
        tile_transpose(We2, We2t, DIN, DD, bx >> 5, bx & 31);
    } else if (bx < 1536) {
        const int lb = bx - 512;
        tile_transpose(Wk, WkT, DD, DD, lb >> 5, lb & 31);
    } else {
        const int b = bx - 1536;
#pragma unroll
        for (int k = 0; k < 4; ++k) {
            const int c = k * 256 + threadIdx.x;
            x1e[(size_t)b * DD + c] = be1[c];
            qb[(size_t)b * DD + c]  = bq[c];
            av[(size_t)b * DD + c]  = bv[c];
            out[(size_t)b * DD + c] = bo[c];
        }
    }
}

// out[r][c] (+)= sum_i in[r][i]*W[i][c] for 16 rows r = by*16..+16.
// grid (N/64, R/16, KS). KS==1: plain store (+bias). KS>1: atomicAdd into
// bias-initialized out (few-thousand atomics only — cheap).
template <int K, int N, int KS, bool HASB>
__global__ __launch_bounds__(256) void k_bmv2(const float* __restrict__ in,
                                              const float* __restrict__ W,
                                              const float* __restrict__ bias,
                                              float* __restrict__ out) {
    const int l = threadIdx.x & 63;
    const int c = blockIdx.x * 64 + l;
    const int wv = wave_id();
    constexpr int KCH = K / KS;
    constexpr int SUB = KCH / 4;
    const float* inb = in + (size_t)blockIdx.y * 16 * K;  // uniform -> s_load
    float acc[16];
#pragma unroll
    for (int r = 0; r < 16; ++r) acc[r] = 0.f;
    const int i0 = blockIdx.z * KCH + wv * SUB;
#pragma unroll 4
    for (int i = i0; i < i0 + SUB; ++i) {
        const float wval = W[(size_t)i * N + c];  // coalesced 256B/wave
#pragma unroll
        for (int r = 0; r < 16; ++r) acc[r] += inb[(size_t)r * K + i] * wval;
    }
    __shared__ float red[4][16][64];
#pragma unroll
    for (int r = 0; r < 16; ++r) red[wv][r][l] = acc[r];
    __syncthreads();
#pragma unroll
    for (int k = 0; k < 4; ++k) {
        const int r = wv + k * 4;
        float v = red[0][r][l] + red[1][r][l] + red[2][r][l] + red[3][r][l];
        float* dst = out + ((size_t)blockIdx.y * 16 + r) * N + c;
        if (KS == 1) {
            if (HASB) v += bias[c];
            *dst = v;
        } else {
            atomicAdd(dst, v);
        }
    }
}

// u[b*16+h][c] = sum_d q[b][h*64+d]*WkT[h*64+d][c].  grid (1024/64, 16 h).
__global__ __launch_bounds__(256) void k_u2(const float* __restrict__ q,
                                            const float* __restrict__ WkT,
                                            float* __restrict__ u) {
    const int h = blockIdx.y;
    const int l = threadIdx.x & 63;
    const int c = blockIdx.x * 64 + l;
    const int wv = wave_id();
    float acc[16];
#pragma unroll
    for (int bb = 0; bb < 16; ++bb) acc[bb] = 0.f;
#pragma unroll 4
    for (int dk = 0; dk < 16; ++dk) {
        const int d = wv * 16 + dk;
        const float wval = WkT[(size_t)(h * HD + d) * DD + c];  // coalesced
#pragma unroll
        for (int bb = 0; bb < 16; ++bb)
            acc[bb] += q[(size_t)bb * DD + h * HD + d] * wval;  // s_load
    }
    __shared__ float red[4][16][64];
#pragma unroll
    for (int bb = 0; bb < 16; ++bb) red[wv][bb][l] = acc[bb];
    __syncthreads();
#pragma unroll
    for (int k = 0; k < 4; ++k) {
        const int bb = wv + k * 4;
        float v = red[0][bb][l] + red[1][bb][l] + red[2][bb][l] + red[3][bb][l];
        u[((size_t)bb * NH + h) * DD + c] = v;
    }
}

// score[b][h][s] = x2[b][s][:].w[b][h][:].  grid (4096/64, 16 b), block 256.
// Stage 64 rows x 128 cols of x2 into LDS with row stride 33 float4s:
// write banks 4*(row+c4)%32 and read banks 4*(l+c4)%32 are both uniform
// across the wave -> conflict-free. w reads are wave-uniform -> s_load.
__global__ __launch_bounds__(256) void k_scores(const float* __restrict__ x2,
                                                const float* __restrict__ w,
                                                float* __restrict__ sc) {
    __shared__ float4 tile[64 * 33];  // 33KB
    const int b = blockIdx.y;
    const int s0 = blockIdx.x * 64;
    const int l = threadIdx.x & 63;
    const int h0 = wave_id() * 4;
    const float4* x2f = (const float4*)x2 + ((size_t)b * SS + s0) * (DIN / 4);
    const float4* wp = (const float4*)(w + ((size_t)b * NH + h0) * DIN);
    float a0 = 0.f, a1 = 0.f, a2 = 0.f, a3 = 0.f;
    for (int kt = 0; kt < 4; ++kt) {
        __syncthreads();
#pragma unroll
        for (int k = 0; k < 8; ++k) {
            const int idx = threadIdx.x + k * 256;
            const int row = idx >> 5, c4 = idx & 31;
            tile[row * 33 + c4] = x2f[row * (DIN / 4) + kt * 32 + c4];
        }
        __syncthreads();
#pragma unroll 8
        for (int c4 = 0; c4 < 32; ++c4) {
            const float4 x = tile[l * 33 + c4];
            const float4 q0 = wp[kt * 32 + c4];            // uniform -> s_load
            const float4 q1 = wp[128 + kt * 32 + c4];
            const float4 q2 = wp[256 + kt * 32 + c4];
            const float4 q3 = wp[384 + kt * 32 + c4];
            a0 += x.x * q0.x + x.y * q0.y + x.z * q0.z + x.w * q0.w;
            a1 += x.x * q1.x + x.y * q1.y + x.z * q1.z + x.w * q1.w;
            a2 += x.x * q2.x + x.y * q2.y + x.z * q2.z + x.w * q2.w;
            a3 += x.x * q3.x + x.y * q3.y + x.z * q3.z + x.w * q3.w;
        }
    }
    const size_t base = ((size_t)b * NH + h0) * SS + s0 + l;
    sc[base + 0 * SS] = a0;
    sc[base + 1 * SS] = a1;
    sc[base + 2 * SS] = a2;
    sc[base + 3 * SS] = a3;
}

// In-place softmax over rows of 4096 (logit scale 1/8), float4 I/O. grid 256.
__global__ __launch_bounds__(256) void k_softmax(float* __restrict__ sc) {
    float4* row = (float4*)(sc + (size_t)blockIdx.x * SS);
    float4 v[4];
    float m = -1e30f;
#pragma unroll
    for (int j = 0; j < 4; ++j) {
        v[j] = row[threadIdx.x + j * 256];
        m = fmaxf(m, fmaxf(fmaxf(v[j].x, v[j].y), fmaxf(v[j].z, v[j].w)));
    }
    __shared__ float red[256];
    red[threadIdx.x] = m;
    __syncthreads();
    for (int s = 128; s > 0; s >>= 1) {
        if (threadIdx.x < (unsigned)s)
            red[threadIdx.x] = fmaxf(red[threadIdx.x], red[threadIdx.x + s]);
        __syncthreads();
    }
    m = red[0];
    __syncthreads();
    float sum = 0.f;
#pragma unroll
    for (int j = 0; j < 4; ++j) {
        v[j].x = expf((v[j].x - m) * 0.125f);
        v[j].y = expf((v[j].y - m) * 0.125f);
        v[j].z = expf((v[j].z - m) * 0.125f);
        v[j].w = expf((v[j].w - m) * 0.125f);
        sum += v[j].x + v[j].y + v[j].z + v[j].w;
    }
    red[threadIdx.x] = sum;
    __syncthreads();
    for (int s = 128; s > 0; s >>= 1) {
        if (threadIdx.x < (unsigned)s) red[threadIdx.x] += red[threadIdx.x + s];
        __syncthreads();
    }
    const float inv = 1.f / red[0];
#pragma unroll
    for (int j = 0; j < 4; ++j) {
        v[j].x *= inv; v[j].y *= inv; v[j].z *= inv; v[j].w *= inv;
        row[threadIdx.x + j * 256] = v[j];
    }
}

// gpart[b][ch][h][i]: partial of g = sum_s a[b][h][s]*x3[b][s][i].
// grid (nch, 16 b), block 256. Wave owns its own s-subrange for ALL 16
// heads; lane covers cols l*4..+4 and 256+l*4..+4 (contiguous 1KB wave
// loads). Plain partial stores to gp (NO global atomics — R4 regression).
__global__ __launch_bounds__(256) void k_gpart(const float* __restrict__ x3,
                                               const float* __restrict__ a,
                                               float* __restrict__ gp,
                                               int schunk, int nch) {
    const int b = blockIdx.y, ch = blockIdx.x;
    const int wv = wave_id();
    const int l = threadIdx.x & 63;
    const int sub = schunk >> 2;
    const int sbeg = ch * schunk + wv * sub;
    const float* ar = a + (size_t)b * NH * SS;  // uniform
    float acc[16][8];
#pragma unroll
    for (int h = 0; h < 16; ++h)
#pragma unroll
        for (int j = 0; j < 8; ++j) acc[h][j] = 0.f;

#pragma unroll 2
    for (int s = sbeg; s < sbeg + sub; ++s) {
        const float4* xr = (const float4*)(x3 + ((size_t)b * SS + s) * DIN);
        const float4 xa = xr[l];
        const float4 xb = xr[l + 64];
        const float xv[8] = {xa.x, xa.y, xa.z, xa.w, xb.x, xb.y, xb.z, xb.w};
#pragma unroll
        for (int h = 0; h < 16; ++h) {
            const float wh = ar[h * SS + s];  // uniform -> s_load
#pragma unroll
            for (int j = 0; j < 8; ++j) acc[h][j] += wh * xv[j];
        }
    }

    __shared__ float red[4][2048];  // 32KB, reused for 4 head-groups
    for (int hg = 0; hg < 4; ++hg) {
        __syncthreads();
#pragma unroll
        for (int hh = 0; hh < 4; ++hh) {
            float* dst = &red[wv][hh * 512];
            const int hs = hg * 4 + hh;
            *(float4*)(dst + l * 4) =
                make_float4(acc[hs][0], acc[hs][1], acc[hs][2], acc[hs][3]);
            *(float4*)(dst + 256 + l * 4) =
                make_float4(acc[hs][4], acc[hs][5], acc[hs][6], acc[hs][7]);
        }
        __syncthreads();
        const int idx = threadIdx.x * 8;
        float o[8];
#pragma unroll
        for (int j = 0; j < 8; ++j)
            o[j] = red[0][idx + j] + red[1][idx + j] + red[2][idx + j] + red[3][idx + j];
        const int hh = idx >> 9;
        const int i = idx & 511;
        float* dst = gp + (((size_t)(b * nch + ch) * NH) + hg * 4 + hh) * DIN + i;
        *(float4*)dst = make_float4(o[0], o[1], o[2], o[3]);
        *(float4*)(dst + 4) = make_float4(o[4], o[5], o[6], o[7]);
    }
}

// g[pair][i] = sum_ch gpart[b][ch][h][i].  grid 256.
__global__ __launch_bounds__(256) void k_greduce(const float* __restrict__ gp, int nch,
                                                 float* __restrict__ g) {
    const int pair = blockIdx.x;
    const int b = pair >> 4, h = pair & 15;
#pragma unroll
    for (int kk = 0; kk < 2; ++kk) {
        const int i = kk * 256 + threadIdx.x;
        float acc = 0.f;
        for (int ch = 0; ch < nch; ++ch)
            acc += gp[((size_t)(b * nch + ch) * NH + h) * DIN + i];
        g[(size_t)pair * DIN + i] = acc;
    }
}

// av[b][h*64+l] (+)= sum_c G2[b*16+h][c]*Wv[c][h*64+l] over a 128-c chunk.
// grid (16 h, 8 chunks) = 128 blocks; atomicAdd into bv-initialized av.
__global__ __launch_bounds__(256) void k_av_at(const float* __restrict__ G2,
                                               const float* __restrict__ Wv,
                                               float* __restrict__ av) {
    const int h = blockIdx.x;
    const int l = threadIdx.x & 63;
    const int wv = wave_id();
    const int c0 = blockIdx.y * 128 + wv * 32;
    float acc[16];
#pragma unroll
    for (int bb = 0; bb < 16; ++bb) acc[bb] = 0.f;
#pragma unroll 4
    for (int c = c0; c < c0 + 32; ++c) {
        const float wval = Wv[(size_t)c * DD + h * HD + l];  // coalesced
#pragma unroll
        for (int bb = 0; bb < 16; ++bb)
            acc[bb] += G2[((size_t)bb * NH + h) * DD + c] * wval;  // s_load
    }
    __shared__ float red[4][16][64];
#pragma unroll
    for (int bb = 0; bb < 16; ++bb) red[wv][bb][l] = acc[bb];
    __syncthreads();
#pragma unroll
    for (int k = 0; k < 4; ++k) {
        const int bb = wv + k * 4;
        float v = red[0][bb][l] + red[1][bb][l] + red[2][bb][l] + red[3][bb][l];
        atomicAdd(&av[(size_t)bb * DD + h * HD + l], v);
    }
}

extern "C" void kernel_launch(void* const* d_in, const int* in_sizes, int n_in,
                              void* d_out, int out_size, void* d_ws, size_t ws_size,
                              hipStream_t stream) {
    const float* x1  = (const float*)d_in[0];
    const float* x2  = (const float*)d_in[1];
    const float* x3  = (const float*)d_in[2];
    const float* We1 = (const float*)d_in[3];
    const float* be1 = (const float*)d_in[4];
    const float* We2 = (const float*)d_in[5];
    const float* be2 = (const float*)d_in[6];
    const float* Wq  = (const float*)d_in[7];
    const float* bq  = (const float*)d_in[8];
    const float* Wk  = (const float*)d_in[9];
    const float* bk  = (const float*)d_in[10];  // cancels in softmax (unused)
    const float* Wv  = (const float*)d_in[11];
    const float* bv  = (const float*)d_in[12];
    const float* Wo  = (const float*)d_in[13];
    const float* bo  = (const float*)d_in[14];
    (void)bk;
    float* out = (float*)d_out;

    char* ws = (char*)d_ws;
    size_t off = 0;
    auto alloc = [&](size_t bytes) -> void* {
        void* p = ws + off;
        off = (off + bytes + 255) & ~(size_t)255;
        return p;
    };
    float* We2t = (float*)alloc((size_t)DD * DIN * 4);  // [1024][512]
    float* WkT  = (float*)alloc((size_t)DD * DD * 4);   // [1024][1024]
    float* x1e  = (float*)alloc((size_t)BB * DD * 4);
    float* qb   = (float*)alloc((size_t)BB * DD * 4);
    float* u    = (float*)alloc((size_t)BB * NH * DD * 4);
    float* wv_  = (float*)alloc((size_t)BB * NH * DIN * 4);
    float* sc   = (float*)alloc((size_t)BB * NH * SS * 4);
    float* g    = (float*)alloc((size_t)BB * NH * DIN * 4);
    float* G2   = (float*)alloc((size_t)BB * NH * DD * 4);
    float* av   = (float*)alloc((size_t)BB * DD * 4);

    const size_t per_chunk = (size_t)BB * NH * DIN * 4;  // 512 KB
    int nch = 32;
    while (nch > 8 && off + (size_t)nch * per_chunk > ws_size) nch >>= 1;
    float* gp = (float*)alloc((size_t)nch * per_chunk);
    const int schunk = SS / nch;

    // prep: transposes + bias inits (one dispatch)
    k_prep<<<1552, 256, 0, stream>>>(We2, Wk, be1, bq, bv, bo,
                                     We2t, WkT, x1e, qb, av, out);
    // x1e += x1@We1   (K=512, KS=8 -> 128 blocks)
    k_bmv2<DIN, DD, 8, false><<<dim3(DD / 64, 1, 8), 256, 0, stream>>>(x1, We1, nullptr, x1e);
    // qb += x1e@Wq    (K=1024, KS=8 -> 128 blocks)
    k_bmv2<DD, DD, 8, false><<<dim3(DD / 64, 1, 8), 256, 0, stream>>>(x1e, Wq, nullptr, qb);
    k_u2<<<dim3(DD / 64, NH), 256, 0, stream>>>(qb, WkT, u);
    // w = u@We2t      (R=256 -> 128 blocks)
    k_bmv2<DD, DIN, 1, false><<<dim3(DIN / 64, BB * NH / 16, 1), 256, 0, stream>>>(u, We2t, nullptr, wv_);
    k_scores<<<dim3(SS / 64, BB), 256, 0, stream>>>(x2, wv_, sc);
    k_softmax<<<BB * NH, 256, 0, stream>>>(sc);
    k_gpart<<<dim3(nch, BB), 256, 0, stream>>>(x3, sc, gp, schunk, nch);
    k_greduce<<<BB * NH, 256, 0, stream>>>(gp, nch, g);
    // G2 = g@We2+be2  (R=256 -> 256 blocks)
    k_bmv2<DIN, DD, 1, true><<<dim3(DD / 64, BB * NH / 16, 1), 256, 0, stream>>>(g, We2, be2, G2);
    k_av_at<<<dim3(NH, 8), 256, 0, stream>>>(G2, Wv, av);
    // out += av@Wo    (K=1024, KS=8 -> 128 blocks)
    k_bmv2<DD, DD, 8, false><<<dim3(DD / 64, 1, 8), 256, 0, stream>>>(av, Wo, nullptr, out);
}

// Round 6
// 448.962 us; speedup vs baseline: 1.6509x; 1.0374x over previous
//
#include <hip/hip_runtime.h>

// CrossAttention decode, algebraically collapsed (all fp32):
//   q[b,h,:]   = ((x1@We1+be1)@Wq+bq) head-sliced
//   u[b,h,c]   = sum_d WkT[h*64+d,c]*q[b,h,d]
//   w[b,h,i]   = sum_c u[b,h,c]*We2t[c,i]          (K-proj folded)
//   score[b,h,s] = x2[b,s,:].w[b,h,:]              (K-bias cancels in softmax)
//   a = softmax(score/8)
//   g[b,h,i]   = sum_s a[b,h,s]*x3[b,s,i]
//   G2[b,h,c]  = g@We2 + be2;  av = G2@Wv_h + bv;  out = av@Wo + bo
// k_attn fuses scores+softmax+gpart flash-style: per (b, 128-s-chunk) block,
// phase A computes score tiles (conflict-free LDS staging of x2), phase B
// runs per-wave online softmax and accumulates x3-weighted sums; partials
// (gp, m, l) are combined exactly in k_greduce2. Eliminates the 16.8MB sc
// array (67MB of traffic), the softmax kernel, and 2 dispatch boundaries.
// Lessons kept: no per-element global atomics on hot paths (R4); stride-33
// float4 LDS tiles (conflict-free); harness reset (~170us: 537MB 0xAA fill
// @86% peak + d_in restore) is fixed overhead inside the timing window.

#define DIN 512
#define DD  1024
#define NH  16
#define HD  64
#define BB  16
#define SS  4096
#define NCH 32   // s-chunks; schunk = 128

__device__ __forceinline__ int wave_id() {
    return __builtin_amdgcn_readfirstlane((int)(threadIdx.x >> 6));
}

__device__ __forceinline__ void tile_transpose(const float* __restrict__ in,
                                               float* __restrict__ out,
                                               int R, int C, int rblk, int cblk) {
    __shared__ float tl[32][33];
    const int tx = threadIdx.x & 31, ty = threadIdx.x >> 5;  // ty 0..7
    const int c0 = cblk * 32, r0 = rblk * 32;
#pragma unroll
    for (int k = 0; k < 4; ++k)
        tl[ty + k * 8][tx] = in[(size_t)(r0 + ty + k * 8) * C + c0 + tx];
    __syncthreads();
#pragma unroll
    for (int k = 0; k < 4; ++k)
        out[(size_t)(c0 + ty + k * 8) * R + r0 + tx] = tl[tx][ty + k * 8];
}

// One fused prep dispatch: We2/Wk transposes + bias init of atomic targets.
__global__ __launch_bounds__(256) void k_prep(const float* __restrict__ We2,
                                              const float* __restrict__ Wk,
                                              const float* __restrict__ be1,
                                              const float* __restrict__ bq,
                                              const float* __restrict__ bv,
                                              const float* __restrict__ bo,
                                              float* __restrict__ We2t,
                                              float* __restrict__ WkT,
                                              float* __restrict__ x1e,
                                              float* __restrict__ qb,
                                              float* __restrict__ av,
                                              float* __restrict__ out) {
    const int bx = blockIdx.x;
    if (bx < 512) {
        tile_transpose(We2, We2t, DIN, DD, bx >> 5, bx & 31);
    } else if (bx < 1536) {
        const int lb = bx - 512;
        tile_transpose(Wk, WkT, DD, DD, lb >> 5, lb & 31);
    } else {
        const int b = bx - 1536;
#pragma unroll
        for (int k = 0; k < 4; ++k) {
            const int c = k * 256 + threadIdx.x;
            x1e[(size_t)b * DD + c] = be1[c];
            qb[(size_t)b * DD + c]  = bq[c];
            av[(size_t)b * DD + c]  = bv[c];
            out[(size_t)b * DD + c] = bo[c];
        }
    }
}

// out[r][c] (+)= sum_i in[r][i]*W[i][c] for 16 rows. grid (N/64, R/16, KS).
template <int K, int N, int KS, bool HASB>
__global__ __launch_bounds__(256) void k_bmv2(const float* __restrict__ in,
                                              const float* __restrict__ W,
                                              const float* __restrict__ bias,
                                              float* __restrict__ out) {
    const int l = threadIdx.x & 63;
    const int c = blockIdx.x * 64 + l;
    const int wv = wave_id();
    constexpr int KCH = K / KS;
    constexpr int SUB = KCH / 4;
    const float* inb = in + (size_t)blockIdx.y * 16 * K;  // uniform -> s_load
    float acc[16];
#pragma unroll
    for (int r = 0; r < 16; ++r) acc[r] = 0.f;
    const int i0 = blockIdx.z * KCH + wv * SUB;
#pragma unroll 4
    for (int i = i0; i < i0 + SUB; ++i) {
        const float wval = W[(size_t)i * N + c];  // coalesced 256B/wave
#pragma unroll
        for (int r = 0; r < 16; ++r) acc[r] += inb[(size_t)r * K + i] * wval;
    }
    __shared__ float red[4][16][64];
#pragma unroll
    for (int r = 0; r < 16; ++r) red[wv][r][l] = acc[r];
    __syncthreads();
#pragma unroll
    for (int k = 0; k < 4; ++k) {
        const int r = wv + k * 4;
        float v = red[0][r][l] + red[1][r][l] + red[2][r][l] + red[3][r][l];
        float* dst = out + ((size_t)blockIdx.y * 16 + r) * N + c;
        if (KS == 1) {
            if (HASB) v += bias[c];
            *dst = v;
        } else {
            atomicAdd(dst, v);
        }
    }
}

// u[b*16+h][c] = sum_d q[b][h*64+d]*WkT[h*64+d][c].  grid (1024/64, 16 h).
__global__ __launch_bounds__(256) void k_u2(const float* __restrict__ q,
                                            const float* __restrict__ WkT,
                                            float* __restrict__ u) {
    const int h = blockIdx.y;
    const int l = threadIdx.x & 63;
    const int c = blockIdx.x * 64 + l;
    const int wv = wave_id();
    float acc[16];
#pragma unroll
    for (int bb = 0; bb < 16; ++bb) acc[bb] = 0.f;
#pragma unroll 4
    for (int dk = 0; dk < 16; ++dk) {
        const int d = wv * 16 + dk;
        const float wval = WkT[(size_t)(h * HD + d) * DD + c];  // coalesced
#pragma unroll
        for (int bb = 0; bb < 16; ++bb)
            acc[bb] += q[(size_t)bb * DD + h * HD + d] * wval;  // s_load
    }
    __shared__ float red[4][16][64];
#pragma unroll
    for (int bb = 0; bb < 16; ++bb) red[wv][bb][l] = acc[bb];
    __syncthreads();
#pragma unroll
    for (int k = 0; k < 4; ++k) {
        const int bb = wv + k * 4;
        float v = red[0][bb][l] + red[1][bb][l] + red[2][bb][l] + red[3][bb][l];
        u[((size_t)bb * NH + h) * DD + c] = v;
    }
}

// Fused scores+softmax+PV: grid (NCH, 16 b), block 256 (4 waves).
// Per 64-s tile: phase A computes scores (wave = 4 heads, lane = s-row,
// x2 staged in stride-33 LDS), parks them in scb. Phase B: wave wv owns
// s-rows wv*16..+16 for ALL 16 heads, lane owns 8 i-cols; online softmax
// (running m,l per head) weights x3 rows into acc[16][8]. Block combine
// rescales waves to a common max; writes gp partial + (m,l) per head.
__global__ __launch_bounds__(256) void k_attn(const float* __restrict__ x2,
                                              const float* __restrict__ x3,
                                              const float* __restrict__ w,
                                              float* __restrict__ gp,
                                              float* __restrict__ mls) {
    __shared__ __align__(16) char smem[64 * 33 * 16 + 16 * 64 * 4];  // 37.9KB
    float4* tile = (float4*)smem;                    // 33.8KB (phase A)
    float*  scb  = (float*)(smem + 64 * 33 * 16);    // 4KB scores [h][s]
    float*  red  = (float*)smem;                     // 32KB (combine; tile dead)
    __shared__ float sm[4][16], sl[4][16];

    const int b = blockIdx.y, ch = blockIdx.x;
    const int l = threadIdx.x & 63;
    const int wv = wave_id();
    const int h0 = wv * 4;
    const float4* wp = (const float4*)(w + ((size_t)b * NH + h0) * DIN);

    float m[16], lsum[16], acc[16][8];
#pragma unroll
    for (int h = 0; h < 16; ++h) {
        m[h] = -1e30f; lsum[h] = 0.f;
#pragma unroll
        for (int j = 0; j < 8; ++j) acc[h][j] = 0.f;
    }

    for (int t = 0; t < 2; ++t) {
        const int s0 = ch * 128 + t * 64;
        // ---- phase A: scores for rows s0..s0+64 ----
        const float4* x2f = (const float4*)x2 + ((size_t)b * SS + s0) * (DIN / 4);
        float a0 = 0.f, a1 = 0.f, a2 = 0.f, a3 = 0.f;
        for (int kt = 0; kt < 4; ++kt) {
            __syncthreads();  // also guards scb reads of previous tile
#pragma unroll
            for (int k = 0; k < 8; ++k) {
                const int idx = threadIdx.x + k * 256;
                const int row = idx >> 5, c4 = idx & 31;
                tile[row * 33 + c4] = x2f[row * (DIN / 4) + kt * 32 + c4];
            }
            __syncthreads();
#pragma unroll 8
            for (int c4 = 0; c4 < 32; ++c4) {
                const float4 x = tile[l * 33 + c4];
                const float4 q0 = wp[kt * 32 + c4];            // uniform
                const float4 q1 = wp[128 + kt * 32 + c4];
                const float4 q2 = wp[256 + kt * 32 + c4];
                const float4 q3 = wp[384 + kt * 32 + c4];
                a0 += x.x * q0.x + x.y * q0.y + x.z * q0.z + x.w * q0.w;
                a1 += x.x * q1.x + x.y * q1.y + x.z * q1.z + x.w * q1.w;
                a2 += x.x * q2.x + x.y * q2.y + x.z * q2.z + x.w * q2.w;
                a3 += x.x * q3.x + x.y * q3.y + x.z * q3.z + x.w * q3.w;
            }
        }
        scb[(h0 + 0) * 64 + l] = a0;
        scb[(h0 + 1) * 64 + l] = a1;
        scb[(h0 + 2) * 64 + l] = a2;
        scb[(h0 + 3) * 64 + l] = a3;
        __syncthreads();

        // ---- phase B: online softmax + PV for rows sq..sq+16, all heads ----
        const int sq = wv * 16;
        float tm[16];
#pragma unroll
        for (int h = 0; h < 16; ++h) {
            float mm = -1e30f;
#pragma unroll
            for (int j = 0; j < 16; ++j) mm = fmaxf(mm, scb[h * 64 + sq + j]);
            tm[h] = mm * 0.125f;
        }
#pragma unroll
        for (int h = 0; h < 16; ++h) {
            const float mn = fmaxf(m[h], tm[h]);
            const float f = __expf(m[h] - mn);
            m[h] = mn; lsum[h] *= f;
#pragma unroll
            for (int j = 0; j < 8; ++j) acc[h][j] *= f;
        }
        for (int j = 0; j < 16; ++j) {
            const int s = s0 + sq + j;
            const float4* xr = (const float4*)(x3 + ((size_t)b * SS + s) * DIN);
            const float4 xa = xr[l];
            const float4 xb = xr[l + 64];
            const float xv[8] = {xa.x, xa.y, xa.z, xa.w, xb.x, xb.y, xb.z, xb.w};
#pragma unroll
            for (int h = 0; h < 16; ++h) {
                const float e = __expf(scb[h * 64 + sq + j] * 0.125f - m[h]);
                lsum[h] += e;
#pragma unroll
                for (int jj = 0; jj < 8; ++jj) acc[h][jj] += e * xv[jj];
            }
        }
    }

    // ---- block combine: rescale all waves to common per-head max ----
#pragma unroll
    for (int h = 0; h < 16; ++h) sm[wv][h] = m[h];
    __syncthreads();
#pragma unroll
    for (int h = 0; h < 16; ++h) {
        const float bmh = fmaxf(fmaxf(sm[0][h], sm[1][h]), fmaxf(sm[2][h], sm[3][h]));
        const float f = __expf(m[h] - bmh);
        lsum[h] *= f;
#pragma unroll
        for (int j = 0; j < 8; ++j) acc[h][j] *= f;
    }
#pragma unroll
    for (int h = 0; h < 16; ++h) sl[wv][h] = lsum[h];

#pragma unroll
    for (int hg = 0; hg < 4; ++hg) {
        __syncthreads();
#pragma unroll
        for (int hh = 0; hh < 4; ++hh) {
            const int hs = hg * 4 + hh;
            float* dst = &red[wv * 2048 + hh * 512];
            *(float4*)(dst + l * 4) =
                make_float4(acc[hs][0], acc[hs][1], acc[hs][2], acc[hs][3]);
            *(float4*)(dst + 256 + l * 4) =
                make_float4(acc[hs][4], acc[hs][5], acc[hs][6], acc[hs][7]);
        }
        __syncthreads();
        const int idx = threadIdx.x * 8;
        const int hh = idx >> 9;
        const int i = idx & 511;
        float o[8];
#pragma unroll
        for (int j = 0; j < 8; ++j)
            o[j] = red[0 * 2048 + idx + j] + red[1 * 2048 + idx + j] +
                   red[2 * 2048 + idx + j] + red[3 * 2048 + idx + j];
        float* dstg = gp + (((size_t)(b * NCH + ch) * NH) + hg * 4 + hh) * DIN + i;
        *(float4*)dstg = make_float4(o[0], o[1], o[2], o[3]);
        *(float4*)(dstg + 4) = make_float4(o[4], o[5], o[6], o[7]);
    }
    if (threadIdx.x < 16) {
        const int h = threadIdx.x;
        const float bmh = fmaxf(fmaxf(sm[0][h], sm[1][h]), fmaxf(sm[2][h], sm[3][h]));
        const float L = sl[0][h] + sl[1][h] + sl[2][h] + sl[3][h];
        float* dst = mls + (((size_t)b * NCH + ch) * NH + h) * 2;
        dst[0] = bmh;
        dst[1] = L;
    }
}

// Flash combine: g[b*16+h][i] = sum_ch exp(m_ch-M)*gp_ch[i] / sum_ch exp(m_ch-M)*l_ch
__global__ __launch_bounds__(256) void k_greduce2(const float* __restrict__ gp,
                                                  const float* __restrict__ mls,
                                                  float* __restrict__ g) {
    const int pair = blockIdx.x;  // 256
    const int b = pair >> 4, h = pair & 15;
    float M = -1e30f;
    for (int ch = 0; ch < NCH; ++ch)
        M = fmaxf(M, mls[(((size_t)b * NCH + ch) * NH + h) * 2]);
    float fch[NCH];
    float L = 0.f;
    for (int ch = 0; ch < NCH; ++ch) {
        const float* p = mls + (((size_t)b * NCH + ch) * NH + h) * 2;
        const float f = __expf(p[0] - M);
        fch[ch] = f;
        L += f * p[1];
    }
    const float invL = 1.f / L;
#pragma unroll
    for (int kk = 0; kk < 2; ++kk) {
        const int i = kk * 256 + threadIdx.x;
        float acc = 0.f;
        for (int ch = 0; ch < NCH; ++ch)
            acc += fch[ch] * gp[((size_t)(b * NCH + ch) * NH + h) * DIN + i];
        g[(size_t)pair * DIN + i] = acc * invL;
    }
}

// av[b][h*64+l] (+)= sum_c G2[b*16+h][c]*Wv[c][h*64+l] over a 128-c chunk.
__global__ __launch_bounds__(256) void k_av_at(const float* __restrict__ G2,
                                               const float* __restrict__ Wv,
                                               float* __restrict__ av) {
    const int h = blockIdx.x;
    const int l = threadIdx.x & 63;
    const int wv = wave_id();
    const int c0 = blockIdx.y * 128 + wv * 32;
    float acc[16];
#pragma unroll
    for (int bb = 0; bb < 16; ++bb) acc[bb] = 0.f;
#pragma unroll 4
    for (int c = c0; c < c0 + 32; ++c) {
        const float wval = Wv[(size_t)c * DD + h * HD + l];  // coalesced
#pragma unroll
        for (int bb = 0; bb < 16; ++bb)
            acc[bb] += G2[((size_t)bb * NH + h) * DD + c] * wval;  // s_load
    }
    __shared__ float red[4][16][64];
#pragma unroll
    for (int bb = 0; bb < 16; ++bb) red[wv][bb][l] = acc[bb];
    __syncthreads();
#pragma unroll
    for (int k = 0; k < 4; ++k) {
        const int bb = wv + k * 4;
        float v = red[0][bb][l] + red[1][bb][l] + red[2][bb][l] + red[3][bb][l];
        atomicAdd(&av[(size_t)bb * DD + h * HD + l], v);
    }
}

extern "C" void kernel_launch(void* const* d_in, const int* in_sizes, int n_in,
                              void* d_out, int out_size, void* d_ws, size_t ws_size,
                              hipStream_t stream) {
    const float* x1  = (const float*)d_in[0];
    const float* x2  = (const float*)d_in[1];
    const float* x3  = (const float*)d_in[2];
    const float* We1 = (const float*)d_in[3];
    const float* be1 = (const float*)d_in[4];
    const float* We2 = (const float*)d_in[5];
    const float* be2 = (const float*)d_in[6];
    const float* Wq  = (const float*)d_in[7];
    const float* bq  = (const float*)d_in[8];
    const float* Wk  = (const float*)d_in[9];
    const float* bk  = (const float*)d_in[10];  // cancels in softmax (unused)
    const float* Wv  = (const float*)d_in[11];
    const float* bv  = (const float*)d_in[12];
    const float* Wo  = (const float*)d_in[13];
    const float* bo  = (const float*)d_in[14];
    (void)bk;
    float* out = (float*)d_out;

    char* ws = (char*)d_ws;
    size_t off = 0;
    auto alloc = [&](size_t bytes) -> void* {
        void* p = ws + off;
        off = (off + bytes + 255) & ~(size_t)255;
        return p;
    };
    float* We2t = (float*)alloc((size_t)DD * DIN * 4);  // [1024][512]
    float* WkT  = (float*)alloc((size_t)DD * DD * 4);   // [1024][1024]
    float* x1e  = (float*)alloc((size_t)BB * DD * 4);
    float* qb   = (float*)alloc((size_t)BB * DD * 4);
    float* u    = (float*)alloc((size_t)BB * NH * DD * 4);
    float* wv_  = (float*)alloc((size_t)BB * NH * DIN * 4);
    float* g    = (float*)alloc((size_t)BB * NH * DIN * 4);
    float* G2   = (float*)alloc((size_t)BB * NH * DD * 4);
    float* av   = (float*)alloc((size_t)BB * DD * 4);
    float* gp   = (float*)alloc((size_t)BB * NCH * NH * DIN * 4);  // 16MB
    float* mls  = (float*)alloc((size_t)BB * NCH * NH * 2 * 4);

    // prep: transposes + bias inits (one dispatch)
    k_prep<<<1552, 256, 0, stream>>>(We2, Wk, be1, bq, bv, bo,
                                     We2t, WkT, x1e, qb, av, out);
    // x1e += x1@We1   (K=512, KS=8 -> 128 blocks)
    k_bmv2<DIN, DD, 8, false><<<dim3(DD / 64, 1, 8), 256, 0, stream>>>(x1, We1, nullptr, x1e);
    // qb += x1e@Wq    (K=1024, KS=8 -> 128 blocks)
    k_bmv2<DD, DD, 8, false><<<dim3(DD / 64, 1, 8), 256, 0, stream>>>(x1e, Wq, nullptr, qb);
    k_u2<<<dim3(DD / 64, NH), 256, 0, stream>>>(qb, WkT, u);
    // w = u@We2t      (R=256 -> 128 blocks)
    k_bmv2<DD, DIN, 1, false><<<dim3(DIN / 64, BB * NH / 16, 1), 256, 0, stream>>>(u, We2t, nullptr, wv_);
    // fused scores + online softmax + PV partials
    k_attn<<<dim3(NCH, BB), 256, 0, stream>>>(x2, x3, wv_, gp, mls);
    k_greduce2<<<BB * NH, 256, 0, stream>>>(gp, mls, g);
    // G2 = g@We2+be2  (R=256 -> 256 blocks)
    k_bmv2<DIN, DD, 1, true><<<dim3(DD / 64, BB * NH / 16, 1), 256, 0, stream>>>(g, We2, be2, G2);
    k_av_at<<<dim3(NH, 8), 256, 0, stream>>>(G2, Wv, av);
    // out += av@Wo    (K=1024, KS=8 -> 128 blocks)
    k_bmv2<DD, DD, 8, false><<<dim3(DD / 64, 1, 8), 256, 0, stream>>>(av, Wo, nullptr, out);
}